// Round 1
// 6113.985 us; speedup vs baseline: 2.9547x; 2.9547x over previous
//
#include <hip/hip_runtime.h>
#include <hip/hip_bf16.h>
#include <math.h>

// GPT-2 forward: L=12, H=12, C=768, T=1024, V=50257, B=2, HD=64
#define TSEQ 1024
#define NBATCH 2
#define NHEAD 12
#define CDIM 768
#define NLAYER 12
#define VOCAB 50257
#define ROWS (NBATCH * TSEQ)   // 2048

typedef __attribute__((ext_vector_type(8))) short bf16x8;
typedef __attribute__((ext_vector_type(4))) float f32x4;

__device__ inline short f2bf(float f) {
    union { __hip_bfloat16 h; short s; } u;
    u.h = __float2bfloat16(f);
    return u.s;
}

// ---------------------------------------------------------------- embedding
__global__ __launch_bounds__(256) void embed_kernel(
    const int* __restrict__ idx, const float* __restrict__ tok,
    const float* __restrict__ pos, float* __restrict__ x)
{
    int row = blockIdx.x;                 // 0..2047  (b*T + t)
    int t = row & (TSEQ - 1);
    int token = idx[row];
    const float* tr = tok + (size_t)token * CDIM;
    const float* pr = pos + (size_t)t * CDIM;
    float* xr = x + (size_t)row * CDIM;
    for (int c = threadIdx.x; c < CDIM; c += 256)
        xr[c] = tr[c] + pr[c];
}

// ---------------------------------------------------------------- layernorm
// one block per row; C=768 = 3*256
__global__ __launch_bounds__(256) void ln_kernel(
    const float* __restrict__ x, const float* __restrict__ w,
    const float* __restrict__ b, __hip_bfloat16* __restrict__ out)
{
    int row = blockIdx.x;
    int tid = threadIdx.x;
    const float* xr = x + (size_t)row * CDIM;
    float v0 = xr[tid], v1 = xr[tid + 256], v2 = xr[tid + 512];
    float s = v0 + v1 + v2;
    #pragma unroll
    for (int off = 32; off; off >>= 1) s += __shfl_xor(s, off);
    __shared__ float red1[4], red2[4];
    int wave = tid >> 6;
    if ((tid & 63) == 0) red1[wave] = s;
    __syncthreads();
    float mean = (red1[0] + red1[1] + red1[2] + red1[3]) * (1.0f / CDIM);
    float d0 = v0 - mean, d1 = v1 - mean, d2 = v2 - mean;
    float sq = d0 * d0 + d1 * d1 + d2 * d2;
    #pragma unroll
    for (int off = 32; off; off >>= 1) sq += __shfl_xor(sq, off);
    if ((tid & 63) == 0) red2[wave] = sq;
    __syncthreads();
    float var = (red2[0] + red2[1] + red2[2] + red2[3]) * (1.0f / CDIM);
    float rstd = rsqrtf(var + 1e-5f);
    __hip_bfloat16* orow = out + (size_t)row * CDIM;
    orow[tid]       = __float2bfloat16(d0 * rstd * w[tid]       + b[tid]);
    orow[tid + 256] = __float2bfloat16(d1 * rstd * w[tid + 256] + b[tid + 256]);
    orow[tid + 512] = __float2bfloat16(d2 * rstd * w[tid + 512] + b[tid + 512]);
}

// ---------------------------------------------------------------- attention
// MFMA flash attention: block = (qtile of 64 rows, head h, batch b), 4 waves.
// Wave w owns query rows qt0 + w*16 .. +15. Per 64-key tile:
//   S = Q K^T via mfma_16x16x32_bf16 (Q frags in regs, K staged [key][d] LDS)
//   online softmax (16-lane shfl row reductions), P->bf16 via per-wave LDS
//   O += P V via mfma (V staged transposed [d][key] in LDS)
__global__ __launch_bounds__(256) void attn_kernel(
    const float* __restrict__ qkv, __hip_bfloat16* __restrict__ y)
{
    const int qtile = blockIdx.x;       // 0..15
    const int h = blockIdx.y;
    const int b = blockIdx.z;
    const int tid = threadIdx.x;
    const int lane = tid & 63;
    const int wave = tid >> 6;
    const int l15 = lane & 15;
    const int quad = lane >> 4;

    __shared__ __align__(16) short Ks[64][72];       // [key][d]
    __shared__ __align__(16) short Vt[64][72];       // [d][key]
    __shared__ __align__(16) short Ps[4][16][72];    // per-wave P tile

    const size_t bbase = (size_t)b * TSEQ * (3 * CDIM);
    const int qt0 = qtile * 64;

    // ---- Q fragments (held for the whole kernel): A[m=l15][k=quad*8+j]
    const int qrow = qt0 + wave * 16 + l15;
    const float* qp = qkv + bbase + (size_t)qrow * (3 * CDIM) + h * 64;
    bf16x8 qa[2];
    #pragma unroll
    for (int c = 0; c < 2; ++c) {
        const float* p = qp + c * 32 + quad * 8;
        #pragma unroll
        for (int j = 0; j < 8; ++j) qa[c][j] = f2bf(p[j]);
    }

    float m[4]    = {-INFINITY, -INFINITY, -INFINITY, -INFINITY};
    float lsum[4] = {0.f, 0.f, 0.f, 0.f};
    f32x4 o[4] = {};   // o[n][r]: row quad*4+r, col n*16+l15 (d)

    const int qrel = wave * 16 + quad * 4;   // query row within tile (+r)

    for (int kt = 0; kt <= qtile; ++kt) {
        __syncthreads();   // prior-iter LDS reads complete before overwrite
        // ---- stage K [key][d] and V transposed [d][key]
        const float* kg = qkv + bbase + (size_t)(kt * 64) * (3 * CDIM) + CDIM + h * 64;
        const float* vg = kg + CDIM;
        #pragma unroll
        for (int it = 0; it < 4; ++it) {
            int flat = it * 256 + tid;       // 0..1023
            int r = flat >> 4;               // key row 0..63
            int c4 = (flat & 15) << 2;       // d0: 0,4,..60
            float4 kv4 = *(const float4*)(kg + (size_t)r * (3 * CDIM) + c4);
            short4 ks4;
            ks4.x = f2bf(kv4.x); ks4.y = f2bf(kv4.y);
            ks4.z = f2bf(kv4.z); ks4.w = f2bf(kv4.w);
            *(short4*)&Ks[r][c4] = ks4;
            float4 vv4 = *(const float4*)(vg + (size_t)r * (3 * CDIM) + c4);
            Vt[c4 + 0][r] = f2bf(vv4.x);
            Vt[c4 + 1][r] = f2bf(vv4.y);
            Vt[c4 + 2][r] = f2bf(vv4.z);
            Vt[c4 + 3][r] = f2bf(vv4.w);
        }
        __syncthreads();

        // ---- S = Q K^T  (M=16 rows, N=64 keys, K=64 d)
        f32x4 s[4] = {};
        #pragma unroll
        for (int c = 0; c < 2; ++c) {
            #pragma unroll
            for (int n = 0; n < 4; ++n) {
                bf16x8 kf = *(const bf16x8*)&Ks[n * 16 + l15][c * 32 + quad * 8];
                s[n] = __builtin_amdgcn_mfma_f32_16x16x32_bf16(qa[c], kf, s[n], 0, 0, 0);
            }
        }

        // ---- online softmax
        const bool diag = (kt == qtile);
        #pragma unroll
        for (int r = 0; r < 4; ++r) {
            float rowmax = -INFINITY;
            #pragma unroll
            for (int n = 0; n < 4; ++n) {
                float sv = s[n][r] * 0.125f;   // 1/sqrt(64)
                if (diag && (n * 16 + l15 > qrel + r)) sv = -INFINITY;
                s[n][r] = sv;
                rowmax = fmaxf(rowmax, sv);
            }
            #pragma unroll
            for (int off = 1; off < 16; off <<= 1)
                rowmax = fmaxf(rowmax, __shfl_xor(rowmax, off));
            float mnew = fmaxf(m[r], rowmax);
            float fr = __expf(m[r] - mnew);    // first tile: exp(-inf)=0
            m[r] = mnew;
            float rs = 0.f;
            #pragma unroll
            for (int n = 0; n < 4; ++n) {
                float p = __expf(s[n][r] - mnew);
                s[n][r] = p;
                rs += p;
            }
            #pragma unroll
            for (int off = 1; off < 16; off <<= 1)
                rs += __shfl_xor(rs, off);
            lsum[r] = lsum[r] * fr + rs;
            #pragma unroll
            for (int n = 0; n < 4; ++n) o[n][r] *= fr;
        }

        // ---- P -> bf16, re-fragment via per-wave LDS tile
        #pragma unroll
        for (int r = 0; r < 4; ++r)
            #pragma unroll
            for (int n = 0; n < 4; ++n)
                Ps[wave][quad * 4 + r][n * 16 + l15] = f2bf(s[n][r]);
        __syncthreads();

        // ---- O += P V  (M=16 rows, N=64 d, K=64 keys)
        #pragma unroll
        for (int c = 0; c < 2; ++c) {
            bf16x8 pf = *(const bf16x8*)&Ps[wave][l15][c * 32 + quad * 8];
            #pragma unroll
            for (int n = 0; n < 4; ++n) {
                bf16x8 vf = *(const bf16x8*)&Vt[n * 16 + l15][c * 32 + quad * 8];
                o[n] = __builtin_amdgcn_mfma_f32_16x16x32_bf16(pf, vf, o[n], 0, 0, 0);
            }
        }
    }

    // ---- epilogue: row = quad*4+r, col(d) = n*16+l15
    const int orow0 = qt0 + wave * 16 + quad * 4;
    #pragma unroll
    for (int n = 0; n < 4; ++n) {
        #pragma unroll
        for (int r = 0; r < 4; ++r) {
            y[(size_t)(b * TSEQ + orow0 + r) * CDIM + h * 64 + n * 16 + l15] =
                __float2bfloat16(o[n][r] / lsum[r]);
        }
    }
}

// ---------------------------------------------------------------- GEMM
// C[m,n] = sum_k A[m,k] * B'[k,n]  (+bias, +residual, gelu, bf16-out options)
// A: bf16 [M,K] row-major.
// NT=true : B is f32 [N,K] (row-major, K contiguous)  -> direct staging
// NT=false: B is f32 [K,N] (row-major, N contiguous)  -> transposing staging
// Tile 128x128xBK32, 4 waves, each wave a 64x64 subtile of 4x4 MFMA 16x16x32.
template <bool NT, bool BIAS, bool RES, bool GELU, bool OUTBF>
__global__ __launch_bounds__(256) void gemm_kernel(
    const __hip_bfloat16* __restrict__ A,
    const float* __restrict__ B,
    const float* __restrict__ bias,
    const float* __restrict__ resid,
    float* __restrict__ Cf,
    __hip_bfloat16* __restrict__ Cb,
    int M, int N, int K)
{
    constexpr int BSTR = NT ? 32 : 40;  // pad NN B-tile rows to dodge worst conflicts
    __shared__ __align__(16) short As[128][32];
    __shared__ __align__(16) short Bs[128][BSTR];

    const int tid = threadIdx.x;
    const int lane = tid & 63;
    const int wave = tid >> 6;
    const int wm = (wave >> 1) * 64;
    const int wn = (wave & 1) * 64;
    const int l15 = lane & 15;
    const int quad = lane >> 4;
    const int bn0 = blockIdx.x * 128;
    const int bm0 = blockIdx.y * 128;

    f32x4 acc[4][4] = {};

    for (int k0 = 0; k0 < K; k0 += 32) {
        // ---- stage A tile [128][32] (bf16, direct 16B copies)
        #pragma unroll
        for (int it = 0; it < 2; ++it) {
            int flat = it * 256 + tid;
            int r = flat >> 2;
            int kk = (flat & 3) << 3;
            bf16x8 v = *(const bf16x8*)(A + (size_t)(bm0 + r) * K + k0 + kk);
            *(bf16x8*)&As[r][kk] = v;
        }
        // ---- stage B tile -> Bs[n][k] (bf16)
        if constexpr (NT) {
            #pragma unroll
            for (int it = 0; it < 4; ++it) {
                int flat = it * 256 + tid;
                int n = flat >> 3;
                int kq = (flat & 7) << 2;
                int gn = bn0 + n;
                float4 bv;
                if (gn < N) bv = *(const float4*)(B + (size_t)gn * K + k0 + kq);
                else        bv = make_float4(0.f, 0.f, 0.f, 0.f);
                short4 sv;
                sv.x = f2bf(bv.x); sv.y = f2bf(bv.y);
                sv.z = f2bf(bv.z); sv.w = f2bf(bv.w);
                *(short4*)&Bs[n][kq] = sv;
            }
        } else {
            #pragma unroll
            for (int it = 0; it < 4; ++it) {
                int flat = it * 256 + tid;
                int kr = flat >> 5;             // 0..31
                int n4 = (flat & 31) << 2;      // 0..124
                float4 bv = *(const float4*)(B + (size_t)(k0 + kr) * N + bn0 + n4);
                Bs[n4 + 0][kr] = f2bf(bv.x);
                Bs[n4 + 1][kr] = f2bf(bv.y);
                Bs[n4 + 2][kr] = f2bf(bv.z);
                Bs[n4 + 3][kr] = f2bf(bv.w);
            }
        }
        __syncthreads();

        // ---- fragments + MFMA
        bf16x8 af[4], bfr[4];
        #pragma unroll
        for (int i = 0; i < 4; ++i)
            af[i] = *(const bf16x8*)&As[wm + i * 16 + l15][quad * 8];
        #pragma unroll
        for (int j = 0; j < 4; ++j)
            bfr[j] = *(const bf16x8*)&Bs[wn + j * 16 + l15][quad * 8];
        #pragma unroll
        for (int i = 0; i < 4; ++i)
            #pragma unroll
            for (int j = 0; j < 4; ++j)
                acc[i][j] = __builtin_amdgcn_mfma_f32_16x16x32_bf16(
                    af[i], bfr[j], acc[i][j], 0, 0, 0);
        __syncthreads();
    }

    // ---- epilogue: D row = quad*4 + r, col = l15  (verified m89/m91 mapping)
    #pragma unroll
    for (int i = 0; i < 4; ++i) {
        #pragma unroll
        for (int j = 0; j < 4; ++j) {
            #pragma unroll
            for (int r = 0; r < 4; ++r) {
                int row = bm0 + wm + i * 16 + quad * 4 + r;
                int col = bn0 + wn + j * 16 + l15;
                if (col < N) {
                    float v = acc[i][j][r];
                    if (BIAS) v += bias[col];
                    if (GELU) v = 0.5f * v * (1.0f + erff(v * 0.70710678118f));
                    if (RES)  v += resid[(size_t)row * N + col];
                    if (OUTBF) Cb[(size_t)row * N + col] = __float2bfloat16(v);
                    else       Cf[(size_t)row * N + col] = v;
                }
            }
        }
    }
}

// ---------------------------------------------------------------- launch
extern "C" void kernel_launch(void* const* d_in, const int* in_sizes, int n_in,
                              void* d_out, int out_size, void* d_ws, size_t ws_size,
                              hipStream_t stream)
{
    (void)in_sizes; (void)n_in; (void)out_size; (void)ws_size;

    const int*   idx     = (const int*)d_in[0];
    const float* tok_emb = (const float*)d_in[1];
    const float* pos_emb = (const float*)d_in[2];
    const float* ln1_w   = (const float*)d_in[3];
    const float* ln1_b   = (const float*)d_in[4];
    const float* w_qkv   = (const float*)d_in[5];
    const float* b_qkv   = (const float*)d_in[6];
    const float* w_proj  = (const float*)d_in[7];
    const float* b_proj  = (const float*)d_in[8];
    const float* ln2_w   = (const float*)d_in[9];
    const float* ln2_b   = (const float*)d_in[10];
    const float* w_fc    = (const float*)d_in[11];
    const float* b_fc    = (const float*)d_in[12];
    const float* w_fc2   = (const float*)d_in[13];
    const float* b_fc2   = (const float*)d_in[14];
    const float* lnf_w   = (const float*)d_in[15];
    const float* lnf_b   = (const float*)d_in[16];

    // workspace layout (~44 MB)
    float* x   = (float*)d_ws;                       // [2048, 768]  f32
    float* qkv = x + (size_t)ROWS * CDIM;            // [2048, 2304] f32
    __hip_bfloat16* hbuf = (__hip_bfloat16*)(qkv + (size_t)ROWS * 3 * CDIM); // [2048,768]
    __hip_bfloat16* ybuf = hbuf + (size_t)ROWS * CDIM;                       // [2048,768]
    __hip_bfloat16* ffn  = ybuf + (size_t)ROWS * CDIM;                       // [2048,3072]

    embed_kernel<<<ROWS, 256, 0, stream>>>(idx, tok_emb, pos_emb, x);

    dim3 g_qkv(3 * CDIM / 128, ROWS / 128);
    dim3 g_proj(CDIM / 128, ROWS / 128);
    dim3 g_fc(4 * CDIM / 128, ROWS / 128);
    dim3 g_head((VOCAB + 127) / 128, ROWS / 128);
    dim3 g_attn(TSEQ / 64, NHEAD, NBATCH);

    for (int l = 0; l < NLAYER; ++l) {
        const float* l1w = ln1_w + l * CDIM;
        const float* l1b = ln1_b + l * CDIM;
        const float* l2w = ln2_w + l * CDIM;
        const float* l2b = ln2_b + l * CDIM;
        const float* wqkv_l = w_qkv + (size_t)l * CDIM * 3 * CDIM;
        const float* bqkv_l = b_qkv + (size_t)l * 3 * CDIM;
        const float* wpr_l  = w_proj + (size_t)l * CDIM * CDIM;
        const float* bpr_l  = b_proj + (size_t)l * CDIM;
        const float* wfc_l  = w_fc + (size_t)l * CDIM * 4 * CDIM;
        const float* bfc_l  = b_fc + (size_t)l * 4 * CDIM;
        const float* wf2_l  = w_fc2 + (size_t)l * 4 * CDIM * CDIM;
        const float* bf2_l  = b_fc2 + (size_t)l * CDIM;

        ln_kernel<<<ROWS, 256, 0, stream>>>(x, l1w, l1b, hbuf);
        gemm_kernel<false, true, false, false, false><<<g_qkv, 256, 0, stream>>>(
            hbuf, wqkv_l, bqkv_l, nullptr, qkv, nullptr, ROWS, 3 * CDIM, CDIM);
        attn_kernel<<<g_attn, 256, 0, stream>>>(qkv, ybuf);
        gemm_kernel<false, true, true, false, false><<<g_proj, 256, 0, stream>>>(
            ybuf, wpr_l, bpr_l, x, x, nullptr, ROWS, CDIM, CDIM);
        ln_kernel<<<ROWS, 256, 0, stream>>>(x, l2w, l2b, hbuf);
        gemm_kernel<false, true, false, true, true><<<g_fc, 256, 0, stream>>>(
            hbuf, wfc_l, bfc_l, nullptr, nullptr, ffn, ROWS, 4 * CDIM, CDIM);
        gemm_kernel<false, true, true, false, false><<<g_proj, 256, 0, stream>>>(
            ffn, wf2_l, bf2_l, x, x, nullptr, ROWS, CDIM, 4 * CDIM);
    }

    ln_kernel<<<ROWS, 256, 0, stream>>>(x, lnf_w, lnf_b, hbuf);
    gemm_kernel<true, false, false, false, false><<<g_head, 256, 0, stream>>>(
        hbuf, tok_emb, nullptr, nullptr, (float*)d_out, nullptr, ROWS, VOCAB, CDIM);
}